// Round 12
// baseline (1124.834 us; speedup 1.0000x reference)
//
#include <hip/hip_runtime.h>
#include <math.h>

#define T 65536
#define NCH 32
#define LCHUNK 512
#define CCHUNK 128
#define SB 256            // reverb block length (65536 = 256 blocks of 256)
#define NBLK 256
#define VH 8              // damping FIR taps (damp<=0.4: 0.4^8 ~ 6.5e-4)

// ws layout (float offsets).
#define OFS_A  0          // 32*65536: biquad out -> final pre-pan signal (in-place)
#define OFS_B1 2097152    // 32*65536: compressor target per sample
#define OFS_P  4194304    // 32*64 derived params
#define OFS_M  4196352    // 32*144 chunk transition matrices
#define OFS_V  4200960    // 32*128*12 chunk zero-state finals
#define OFS_Z  4250112    // 32*128*12 chunk initial states

// ---------------- param kernel (also writes p_out) ----------------

__device__ void norm_store(double b0,double b1,double b2,double a0,double a1,double a2,
                           double* B, double* A1, double* A2, int k){
  B[k*3+0]=b0/a0; B[k*3+1]=b1/a0; B[k*3+2]=b2/a0; A1[k]=a1/a0; A2[k]=a2/a0;
}

__device__ void shelf_coefs(double fc, double g, double s, double* B, double* A1, double* A2, int k){
  double A  = pow(10.0, g/40.0);
  double w  = 2.0*3.14159265358979323846*fc/44100.0;
  double cw = cos(w);
  double al = sin(w)*0.70710678118654752;
  double sq = 2.0*sqrt(A)*al;
  double b0 = A*((A+1.0) + s*(A-1.0)*cw + sq);
  double b1 = -2.0*s*A*((A-1.0) + s*(A+1.0)*cw);
  double b2 = A*((A+1.0) + s*(A-1.0)*cw - sq);
  double a0 = (A+1.0) - s*(A-1.0)*cw + sq;
  double a1 = 2.0*s*((A-1.0) - s*(A+1.0)*cw);
  double a2 = (A+1.0) - s*(A-1.0)*cw - sq;
  norm_store(b0,b1,b2,a0,a1,a2,B,A1,A2,k);
}

__device__ void peak_coefs(double fc, double g, double q, double* B, double* A1, double* A2, int k){
  double A  = pow(10.0, g/40.0);
  double w  = 2.0*3.14159265358979323846*fc/44100.0;
  double cw = cos(w);
  double al = sin(w)/(2.0*q);
  norm_store(1.0+al*A, -2.0*cw, 1.0-al*A, 1.0+al/A, -2.0*cw, 1.0-al/A, B,A1,A2,k);
}

__global__ void k_params(const float* __restrict__ p, float* __restrict__ ws, float* __restrict__ pout){
  int ch = threadIdx.x;
  if (ch >= NCH) return;
  const float* pf = p + ch*24;
  float f[24];
  #pragma unroll
  for (int j=0;j<24;j++) f[j]=pf[j];

  double gain_in = (double)f[0]*60.0 - 48.0;
  double hp_fc  = (double)f[1]*350.0;
  double lp_fc  = (double)f[2]*19000.0 + 3000.0;
  double hs_fc  = (double)f[3]*14500.0 + 1500.0;
  double hs_g   = (double)f[4]*30.0 - 15.0;
  double ls_fc  = (double)f[5]*420.0 + 30.0;
  double ls_g   = (double)f[6]*30.0 - 15.0;
  double mh_fc  = (double)f[7]*6400.0 + 600.0;
  double mh_g   = (double)f[8]*30.0 - 15.0;
  double mh_q   = (double)f[9]*2.5 + 0.5;
  double ml_fc  = (double)f[10]*2300.0 + 200.0;
  double ml_g   = (double)f[11]*30.0 - 15.0;
  double ml_q   = (double)f[12]*2.5 + 0.5;
  double c_thr  = (double)f[13]*30.0 - 20.0;
  double c_rat  = (double)f[14]*19.0 + 1.0;
  double c_att  = (double)f[15]*29.0 + 1.0;
  double c_rel  = (double)f[16]*3900.0 + 100.0;
  double gain_out=(double)f[22]*60.0 - 48.0;
  double pan    = (double)f[23]*0.4 + 0.3;

  double B[18], A1[6], A2[6];
  { double K = tan(3.14159265358979323846*hp_fc/44100.0);
    double a1=(K-1.0)/(K+1.0), b0=1.0/(1.0+K);
    B[0]=b0; B[1]=-b0; B[2]=0.0; A1[0]=a1; A2[0]=0.0; }
  { double K = tan(3.14159265358979323846*lp_fc/44100.0);
    double a1=(K-1.0)/(K+1.0), b0=K/(1.0+K);
    B[3]=b0; B[4]=b0; B[5]=0.0; A1[1]=a1; A2[1]=0.0; }
  shelf_coefs(hs_fc, hs_g,  1.0, B, A1, A2, 2);
  shelf_coefs(ls_fc, ls_g, -1.0, B, A1, A2, 3);
  peak_coefs (mh_fc, mh_g, mh_q, B, A1, A2, 4);
  peak_coefs (ml_fc, ml_g, ml_q, B, A1, A2, 5);

  double gin = pow(10.0, gain_in/20.0);
  B[0]*=gin; B[1]*=gin; B[2]*=gin;  // fold input gain into section 0

  float* Pc = ws + OFS_P + ch*64;
  #pragma unroll
  for (int k=0;k<6;k++){
    Pc[k]    = (float)B[k*3+0];
    Pc[6+k]  = (float)B[k*3+1];
    Pc[12+k] = (float)B[k*3+2];
    Pc[18+k] = (float)A1[k];
    Pc[24+k] = (float)A2[k];
  }
  Pc[30] = (float)c_thr;
  Pc[31] = (float)(1.0 - 1.0/c_rat);
  Pc[32] = (float)exp(-1.0/(c_att*0.001*44100.0));
  Pc[33] = (float)exp(-1.0/(c_rel*0.001*44100.0));
  double fb   = (double)f[17]*0.28 + 0.7;
  double damp = (double)f[18]*0.4;
  double wet1 = 3.0*(double)f[19]*0.5*(1.0+(double)f[21]);
  double dryg = 2.0*(double)f[20];
  double gout = pow(10.0, gain_out/20.0);
  Pc[34] = (float)fb;
  Pc[35] = (float)damp;
  Pc[36] = (float)(wet1*gout);
  Pc[37] = (float)(dryg*gout/0.015);   // applied to xt (= comp*0.015)
  Pc[38] = (float)cos(pan*1.57079632679489662);
  Pc[39] = (float)sin(pan*1.57079632679489662);

  float* po = pout + ch*24;
  po[0]=(float)gain_in; po[1]=(float)hp_fc; po[2]=(float)lp_fc; po[3]=(float)hs_fc;
  po[4]=(float)hs_g; po[5]=(float)ls_fc; po[6]=(float)ls_g; po[7]=(float)mh_fc;
  po[8]=(float)mh_g; po[9]=(float)mh_q; po[10]=(float)ml_fc; po[11]=(float)ml_g;
  po[12]=(float)ml_q; po[13]=(float)c_thr; po[14]=(float)c_rat; po[15]=(float)c_att;
  po[16]=(float)c_rel; po[17]=f[17]; po[18]=f[18]; po[19]=f[19]; po[20]=f[20];
  po[21]=f[21]; po[22]=(float)gain_out; po[23]=(float)pan;
}

// ---------------- biquad cascade: chunked linear scan ----------------

__device__ __forceinline__ float bq_step(const float* b0, const float* b1, const float* b2,
                                         const float* a1, const float* a2,
                                         float* z1, float* z2, float s){
  #pragma unroll
  for (int k=0;k<6;k++){
    float y = fmaf(b0[k], s, z1[k]);
    z1[k] = fmaf(b1[k], s, fmaf(-a1[k], y, z2[k]));
    z2[k] = fmaf(b2[k], s, -a2[k]*y);
    s = y;
  }
  return s;
}

__device__ __forceinline__ void load_coefs(const float* Pc, float* b0, float* b1, float* b2,
                                           float* a1, float* a2){
  #pragma unroll
  for (int k=0;k<6;k++){
    b0[k]=Pc[k]; b1[k]=Pc[6+k]; b2[k]=Pc[12+k]; a1[k]=Pc[18+k]; a2[k]=Pc[24+k];
  }
}

__global__ void k_chunk1(const float* __restrict__ x, float* __restrict__ ws){
  int tg = blockIdx.x*64 + threadIdx.x;      // 32 * 140 tasks
  int ch = tg / 140, sub = tg % 140;
  if (ch >= NCH) return;
  const float* Pc = ws + OFS_P + ch*64;
  float b0[6],b1[6],b2[6],a1[6],a2[6];
  load_coefs(Pc,b0,b1,b2,a1,a2);
  float z1[6]={0,0,0,0,0,0}, z2[6]={0,0,0,0,0,0};

  if (sub < CCHUNK){
    const float4* xp = (const float4*)(x + ch*T + sub*LCHUNK);
    for (int j=0;j<LCHUNK/4;j++){
      float4 v = xp[j];
      bq_step(b0,b1,b2,a1,a2,z1,z2,v.x);
      bq_step(b0,b1,b2,a1,a2,z1,z2,v.y);
      bq_step(b0,b1,b2,a1,a2,z1,z2,v.z);
      bq_step(b0,b1,b2,a1,a2,z1,z2,v.w);
    }
    float* vo = ws + OFS_V + (ch*CCHUNK + sub)*12;
    #pragma unroll
    for (int k=0;k<6;k++){ vo[2*k]=z1[k]; vo[2*k+1]=z2[k]; }
  } else {
    int j = sub - CCHUNK;                    // unit state index 0..11
    if ((j & 1)==0) z1[j>>1]=1.0f; else z2[j>>1]=1.0f;
    for (int t=0;t<LCHUNK;t++) bq_step(b0,b1,b2,a1,a2,z1,z2,0.0f);
    float* mo = ws + OFS_M + ch*144 + j*12;  // column j
    #pragma unroll
    for (int k=0;k<6;k++){ mo[2*k]=z1[k]; mo[2*k+1]=z2[k]; }
  }
}

__global__ void k_chunk2(float* __restrict__ ws){
  int ch = threadIdx.x;
  if (ch >= NCH) return;
  const float* M = ws + OFS_M + ch*144;
  const float* V = ws + OFS_V + ch*CCHUNK*12;
  float*       Z = ws + OFS_Z + ch*CCHUNK*12;
  float z[12];
  #pragma unroll
  for (int i=0;i<12;i++) z[i]=0.0f;
  for (int c=0;c<CCHUNK;c++){
    #pragma unroll
    for (int i=0;i<12;i++) Z[c*12+i]=z[i];
    float zn[12];
    #pragma unroll
    for (int i=0;i<12;i++) zn[i]=V[c*12+i];
    #pragma unroll
    for (int j=0;j<12;j++){
      float zj = z[j];
      #pragma unroll
      for (int i=0;i<12;i++) zn[i] = fmaf(M[j*12+i], zj, zn[i]);
    }
    #pragma unroll
    for (int i=0;i<12;i++) z[i]=zn[i];
  }
}

// pass 3: re-run chunks with correct init; write biquad out (A) + target (B1)
__global__ void k_chunk3(const float* __restrict__ x, float* __restrict__ ws){
  int tg = blockIdx.x*64 + threadIdx.x;      // 4096
  int ch = tg >> 7, c = tg & (CCHUNK-1);
  const float* Pc = ws + OFS_P + ch*64;
  float b0[6],b1[6],b2[6],a1[6],a2[6];
  load_coefs(Pc,b0,b1,b2,a1,a2);
  float thr = Pc[30], rt = Pc[31];
  const float* Zi = ws + OFS_Z + (ch*CCHUNK + c)*12;
  float z1[6], z2[6];
  #pragma unroll
  for (int k=0;k<6;k++){ z1[k]=Zi[2*k]; z2[k]=Zi[2*k+1]; }
  const float4* xp = (const float4*)(x + ch*T + c*LCHUNK);
  float4* Ao  = (float4*)(ws + OFS_A  + (size_t)ch*T + c*LCHUNK);
  float4* B1o = (float4*)(ws + OFS_B1 + (size_t)ch*T + c*LCHUNK);
  for (int j=0;j<LCHUNK/4;j++){
    float4 v = xp[j], ya, tb;
    ya.x = bq_step(b0,b1,b2,a1,a2,z1,z2,v.x);
    ya.y = bq_step(b0,b1,b2,a1,a2,z1,z2,v.y);
    ya.z = bq_step(b0,b1,b2,a1,a2,z1,z2,v.z);
    ya.w = bq_step(b0,b1,b2,a1,a2,z1,z2,v.w);
    tb.x = fminf(0.0f, (thr - 6.0205999132796239f*log2f(fabsf(ya.x)+1e-6f))*rt);
    tb.y = fminf(0.0f, (thr - 6.0205999132796239f*log2f(fabsf(ya.y)+1e-6f))*rt);
    tb.z = fminf(0.0f, (thr - 6.0205999132796239f*log2f(fabsf(ya.z)+1e-6f))*rt);
    tb.w = fminf(0.0f, (thr - 6.0205999132796239f*log2f(fabsf(ya.w)+1e-6f))*rt);
    Ao[j]=ya; B1o[j]=tb;
  }
}

// ---------------- fused compressor-scan + freeverb --------------------------
// SB=256 blocks, 2 barriers/iter.
// Waves 0-3: phase A (LDS-only): g recovery, gain, comb gather into dbuf'd
//   haloed cH; phase B1: x prefetch, 8-tap FIR + comb writes (all 256 lanes);
//   allpass ONLY by lanes 0..224 — dual lanes 0..30 are the sole owners of
//   samples tid+225 (stages 1-3 + in-lane stage-4 pair). One writer per slot.
// Wave 4: phase A: write B1st(i+1) from regs; DP for block i+1 with inputs
//   gathered from bR via __shfl (register-only: no same-wave LDS hazard);
//   phase B1: load t(i+2) to bR; lane 256 scans block i+1 from Ild (barrier-
//   separated from the DP writes).

__global__ __launch_bounds__(320) void k_verb(float* __restrict__ ws){
  const int LC[8] = {1116,1188,1277,1356,1422,1491,1557,1617};
  const int COFF[8] = {0,1116,2304,3581,4937,6359,7850,9407};
  const int LA[4] = {556,441,341,225};
  const int AOFF[4] = {0,556,997,1338};
  int ch = blockIdx.x, tid = threadIdx.x;
  __shared__ float cb[11024];
  __shared__ float ab[1563];
  __shared__ float cH[2][8][266];  // dbuf: [p][k][10 halo + 256]
  __shared__ float xts[256];
  __shared__ float accS[256];
  __shared__ float B1st[2][256];   // target staging, dbuf
  __shared__ float Ild[384];       // 32 group records x 12 (9 used)
  __shared__ float gB[2][32];      // group-boundary g, dbuf
  const float* Pc = ws + OFS_P + ch*64;
  float fb = Pc[34], damp = Pc[35], wet1 = Pc[36], dryk = Pc[37];
  float aA = Pc[32], aR = Pc[33];
  float kA = 1.0f - aA, kR = 1.0f - aR;
  float omd = 1.0f - damp;
  float* Aio = ws + OFS_A + (size_t)ch*T;
  const float* B1c = ws + OFS_B1 + (size_t)ch*T;
  for (int i=tid;i<11024;i+=320) cb[i]=0.0f;
  for (int i=tid;i<1563;i+=320)  ab[i]=0.0f;
  for (int i=tid;i<2*8*266;i+=320) ((float*)cH)[i]=0.0f;
  bool scanw = (tid >= 256);
  int sl = tid - 256;
  // FIR weights damp^d
  float w[VH];
  { float pw = 1.0f;
    #pragma unroll
    for (int d=0;d<VH;d++){ w[d]=pw; pw*=damp; } }
  // scan slopes s_j = aA^j aR^(8-j)
  float sj[9];
  { float pA = 1.0f;
    #pragma unroll
    for (int j=0;j<9;j++){ sj[j]=pA; pA*=aA; }
    float pR = 1.0f;
    #pragma unroll
    for (int j=8;j>=0;j--){ sj[j]*=pR; pR*=aR; } }
  int cbb[8] = {0,0,0,0,0,0,0,0};
  int abb[4] = {0,0,0,0};
  float gcarry = 0.0f;
  float4 bR;
  float xv = 0.0f;

  // ---- prologue ----
  if (scanw){
    const float4* bsrc = (const float4*)(B1c);
    float4 b0r = bsrc[sl];       // t(0)
    float4 b1r = bsrc[64+sl];    // t(1)
    ((float4*)B1st[0])[sl] = b0r;
    ((float4*)B1st[1])[sl] = b1r;
    bR = b1r;                    // iter-0 phase-A DP uses bR = t(1)
    // DP(0) from b0r via register crosslane
    int l0 = (sl<<1)&63, l1 = ((sl<<1)|1)&63;
    float Tv[8];
    Tv[0]=__shfl(b0r.x,l0); Tv[1]=__shfl(b0r.y,l0); Tv[2]=__shfl(b0r.z,l0); Tv[3]=__shfl(b0r.w,l0);
    Tv[4]=__shfl(b0r.x,l1); Tv[5]=__shfl(b0r.y,l1); Tv[6]=__shfl(b0r.z,l1); Tv[7]=__shfl(b0r.w,l1);
    if (sl < 32){
      float bb[9];
      bb[0]=kR*Tv[0]; bb[1]=kA*Tv[0];
      #pragma unroll
      for (int s=1;s<8;s++){
        float bA=kA*Tv[s], bRv=kR*Tv[s];
        bb[s+1]=fmaf(aA, bb[s], bA);
        #pragma unroll
        for (int j=7;j>=1;j--) if (j<=s) bb[j]=fminf(fmaf(aA,bb[j-1],bA), fmaf(aR,bb[j],bRv));
        bb[0]=fmaf(aR,bb[0],bRv);
      }
      float* ig=&Ild[sl*12];
      *(float4*)(ig)   = make_float4(bb[0],bb[1],bb[2],bb[3]);
      *(float4*)(ig+4) = make_float4(bb[4],bb[5],bb[6],bb[7]);
      ig[8]=bb[8];
    }
  }
  if (tid < 256) xv = Aio[tid];
  __syncthreads();
  if (tid == 256){
    float g = 0.0f;
    for (int m=0;m<32;m++){
      gB[0][m] = g;
      const float* Ip = &Ild[m*12];
      float f0=fmaf(sj[0],g,Ip[0]), f1=fmaf(sj[1],g,Ip[1]), f2=fmaf(sj[2],g,Ip[2]);
      float f3=fmaf(sj[3],g,Ip[3]), f4=fmaf(sj[4],g,Ip[4]), f5=fmaf(sj[5],g,Ip[5]);
      float f6=fmaf(sj[6],g,Ip[6]), f7=fmaf(sj[7],g,Ip[7]), f8=fmaf(sj[8],g,Ip[8]);
      g = fminf(fminf(fminf(f0,f1),fminf(f2,f3)),
                fminf(fminf(f4,f5),fminf(fminf(f6,f7),f8)));
    }
    gcarry = g;
  }
  __syncthreads();

  for (int i=0;i<NBLK;i++){
    int t0 = i<<8;
    int p = i & 1;
    float xt = 0.0f, acc = 0.0f;
    // ---------- phase A (LDS-only) ----------
    if (tid < 256){
      int m = tid>>3, r = tid&7;
      float g = gB[p][m];
      const float* Bl = B1st[p] + (m<<3);
      #pragma unroll
      for (int s=0;s<8;s++){
        if (s<=r){
          float tt = Bl[s];
          g = fminf(fmaf(aA,g,kA*tt), fmaf(aR,g,kR*tt));
        }
      }
      xt = xv * exp2f(g*0.16609640474436813f) * 0.015f;
      xts[tid] = xt;
      #pragma unroll
      for (int k=0;k<8;k++){
        int idx = cbb[k]+tid; if (idx>=LC[k]) idx-=LC[k];
        float o = cb[COFF[k]+idx];
        float cv = omd*o;
        cH[p][k][10+tid] = cv;
        if (tid >= 246) cH[p^1][k][tid-246] = cv;   // halo for next block
        acc += o;
      }
      accS[tid] = acc;
    } else {
      if (i >= 1 && i+1 < NBLK) ((float4*)B1st[(i+1)&1])[sl] = bR;
      if (i+1 < NBLK){
        int l0 = (sl<<1)&63, l1 = ((sl<<1)|1)&63;
        float Tv[8];
        Tv[0]=__shfl(bR.x,l0); Tv[1]=__shfl(bR.y,l0); Tv[2]=__shfl(bR.z,l0); Tv[3]=__shfl(bR.w,l0);
        Tv[4]=__shfl(bR.x,l1); Tv[5]=__shfl(bR.y,l1); Tv[6]=__shfl(bR.z,l1); Tv[7]=__shfl(bR.w,l1);
        if (sl < 32){
          float bb[9];
          bb[0]=kR*Tv[0]; bb[1]=kA*Tv[0];
          #pragma unroll
          for (int s=1;s<8;s++){
            float bA=kA*Tv[s], bRv=kR*Tv[s];
            bb[s+1]=fmaf(aA, bb[s], bA);
            #pragma unroll
            for (int j=7;j>=1;j--) if (j<=s) bb[j]=fminf(fmaf(aA,bb[j-1],bA), fmaf(aR,bb[j],bRv));
            bb[0]=fmaf(aR,bb[0],bRv);
          }
          float* ig=&Ild[sl*12];
          *(float4*)(ig)   = make_float4(bb[0],bb[1],bb[2],bb[3]);
          *(float4*)(ig+4) = make_float4(bb[4],bb[5],bb[6],bb[7]);
          ig[8]=bb[8];
        }
      }
    }
    __syncthreads();
    // ---------- phase B1 ----------
    if (tid < 256){
      if (i+1 < NBLK) xv = Aio[t0+256+tid];    // prefetch next x (drain covered)
      // FIR damping + comb writes (all 256 lanes)
      #pragma unroll
      for (int k=0;k<8;k++){
        float s = 0.0f;
        #pragma unroll
        for (int d=0;d<VH;d++) s = fmaf(w[d], cH[p][k][10+tid-d], s);
        int idx = cbb[k]+tid; if (idx>=LC[k]) idx-=LC[k];
        cb[COFF[k]+idx] = fmaf(fb, s, xt);
      }
      // allpass: lanes 0..224 own sample tid; dual lanes 0..30 own tid+225 too
      if (tid < 225){
        float a = acc;
        #pragma unroll
        for (int j=0;j<3;j++){
          int idx = abb[j]+tid; if (idx>=LA[j]) idx-=LA[j];
          float bv = ab[AOFF[j]+idx];
          ab[AOFF[j]+idx] = fmaf(0.5f, bv, a);
          a = bv - a;
        }
        bool dual = (tid < 31);
        float a2 = 0.0f, xt2 = 0.0f;
        if (dual){
          a2 = accS[tid+225];
          xt2 = xts[tid+225];
          #pragma unroll
          for (int j=0;j<3;j++){
            int idx = abb[j]+tid+225;
            if (idx>=LA[j]) idx-=LA[j];
            if (idx>=LA[j]) idx-=LA[j];
            float bv = ab[AOFF[j]+idx];
            ab[AOFF[j]+idx] = fmaf(0.5f, bv, a2);
            a2 = bv - a2;
          }
        }
        int idx = abb[3]+tid; if (idx>=225) idx-=225;
        float bv = ab[AOFF[3]+idx];
        float b  = fmaf(0.5f, bv, a);
        float y  = bv - a;
        Aio[t0+tid] = fmaf(y, wet1, xt*dryk);
        if (dual){
          float y2 = b - a2;                 // sample tid+225 sees tid's write
          ab[AOFF[3]+idx] = fmaf(0.5f, b, a2);
          Aio[t0+225+tid] = fmaf(y2, wet1, xt2*dryk);
        } else {
          ab[AOFF[3]+idx] = b;
        }
      }
    } else {
      if (i+2 < NBLK)
        bR = ((const float4*)(B1c + (size_t)(i+2)*SB))[sl];
      if (tid == 256 && i+1 < NBLK){           // scan block i+1
        int q = (i+1)&1;
        float g = gcarry;
        #pragma unroll 4
        for (int m=0;m<32;m++){
          gB[q][m] = g;
          const float* Ip = &Ild[m*12];
          float f0=fmaf(sj[0],g,Ip[0]), f1=fmaf(sj[1],g,Ip[1]), f2=fmaf(sj[2],g,Ip[2]);
          float f3=fmaf(sj[3],g,Ip[3]), f4=fmaf(sj[4],g,Ip[4]), f5=fmaf(sj[5],g,Ip[5]);
          float f6=fmaf(sj[6],g,Ip[6]), f7=fmaf(sj[7],g,Ip[7]), f8=fmaf(sj[8],g,Ip[8]);
          g = fminf(fminf(fminf(f0,f1),fminf(f2,f3)),
                    fminf(fminf(f4,f5),fminf(fminf(f6,f7),f8)));
        }
        gcarry = g;
      }
    }
    #pragma unroll
    for (int k=0;k<8;k++){ cbb[k]+=SB; if (cbb[k]>=LC[k]) cbb[k]-=LC[k]; }
    #pragma unroll
    for (int j=0;j<4;j++){
      abb[j]+=SB;
      if (abb[j]>=LA[j]) abb[j]-=LA[j];
      if (abb[j]>=LA[j]) abb[j]-=LA[j];   // L=225 < SB=256 needs 2nd wrap
    }
    __syncthreads();
  }
}

// ---------------- pan mix ----------------

__global__ void k_mix(const float* __restrict__ ws, float* __restrict__ out){
  int id = blockIdx.x*256 + threadIdx.x;   // 4*65536
  int t = id & (T-1), b = id >> 16;
  const float* Av = ws + OFS_A + (size_t)b*8*T + t;
  const float* P = ws + OFS_P;
  float s0=0.0f, s1=0.0f;
  #pragma unroll
  for (int n=0;n<8;n++){
    float v = Av[(size_t)n*T];
    int ch = b*8+n;
    s0 = fmaf(v, P[ch*64+38], s0);
    s1 = fmaf(v, P[ch*64+39], s1);
  }
  out[b*2*T + t]     = s0;
  out[b*2*T + T + t] = s1;
}

extern "C" void kernel_launch(void* const* d_in, const int* in_sizes, int n_in,
                              void* d_out, int out_size, void* d_ws, size_t ws_size,
                              hipStream_t stream) {
  const float* x = (const float*)d_in[0];
  const float* p = (const float*)d_in[1];
  float* out = (float*)d_out;
  float* ws  = (float*)d_ws;

  k_params<<<1, 64, 0, stream>>>(p, ws, out + 4*2*T);
  k_chunk1<<<70, 64, 0, stream>>>(x, ws);
  k_chunk2<<<1, 64, 0, stream>>>(ws);
  k_chunk3<<<64, 64, 0, stream>>>(x, ws);
  k_verb  <<<NCH, 320, 0, stream>>>(ws);
  k_mix   <<<(4*T)/256, 256, 0, stream>>>(ws, out);
}

// Round 13
// 964.989 us; speedup vs baseline: 1.1656x; 1.1656x over previous
//
#include <hip/hip_runtime.h>
#include <math.h>

#define T 65536
#define NCH 32
#define LCHUNK 512
#define CCHUNK 128
#define SB 256            // reverb block length (65536 = 256 blocks of 256)
#define NBLK 256
#define VH 8              // damping FIR taps (damp<=0.4: 0.4^8 ~ 6.5e-4)

// ws layout (float offsets).
#define OFS_A  0          // 32*65536: biquad out -> final pre-pan signal (in-place)
#define OFS_B1 2097152    // 32*65536: compressor target per sample
#define OFS_I  4194304    // 32*256*384: per-block group records (12 floats/group, 9 used)
#define OFS_P  7340032    // 32*64 derived params
#define OFS_M  7342080    // 32*144 chunk transition matrices
#define OFS_V  7346688    // 32*128*12 chunk zero-state finals
#define OFS_Z  7395840    // 32*128*12 chunk initial states

// ---------------- param kernel (also writes p_out) ----------------

__device__ void norm_store(double b0,double b1,double b2,double a0,double a1,double a2,
                           double* B, double* A1, double* A2, int k){
  B[k*3+0]=b0/a0; B[k*3+1]=b1/a0; B[k*3+2]=b2/a0; A1[k]=a1/a0; A2[k]=a2/a0;
}

__device__ void shelf_coefs(double fc, double g, double s, double* B, double* A1, double* A2, int k){
  double A  = pow(10.0, g/40.0);
  double w  = 2.0*3.14159265358979323846*fc/44100.0;
  double cw = cos(w);
  double al = sin(w)*0.70710678118654752;
  double sq = 2.0*sqrt(A)*al;
  double b0 = A*((A+1.0) + s*(A-1.0)*cw + sq);
  double b1 = -2.0*s*A*((A-1.0) + s*(A+1.0)*cw);
  double b2 = A*((A+1.0) + s*(A-1.0)*cw - sq);
  double a0 = (A+1.0) - s*(A-1.0)*cw + sq;
  double a1 = 2.0*s*((A-1.0) - s*(A+1.0)*cw);
  double a2 = (A+1.0) - s*(A-1.0)*cw - sq;
  norm_store(b0,b1,b2,a0,a1,a2,B,A1,A2,k);
}

__device__ void peak_coefs(double fc, double g, double q, double* B, double* A1, double* A2, int k){
  double A  = pow(10.0, g/40.0);
  double w  = 2.0*3.14159265358979323846*fc/44100.0;
  double cw = cos(w);
  double al = sin(w)/(2.0*q);
  norm_store(1.0+al*A, -2.0*cw, 1.0-al*A, 1.0+al/A, -2.0*cw, 1.0-al/A, B,A1,A2,k);
}

__global__ void k_params(const float* __restrict__ p, float* __restrict__ ws, float* __restrict__ pout){
  int ch = threadIdx.x;
  if (ch >= NCH) return;
  const float* pf = p + ch*24;
  float f[24];
  #pragma unroll
  for (int j=0;j<24;j++) f[j]=pf[j];

  double gain_in = (double)f[0]*60.0 - 48.0;
  double hp_fc  = (double)f[1]*350.0;
  double lp_fc  = (double)f[2]*19000.0 + 3000.0;
  double hs_fc  = (double)f[3]*14500.0 + 1500.0;
  double hs_g   = (double)f[4]*30.0 - 15.0;
  double ls_fc  = (double)f[5]*420.0 + 30.0;
  double ls_g   = (double)f[6]*30.0 - 15.0;
  double mh_fc  = (double)f[7]*6400.0 + 600.0;
  double mh_g   = (double)f[8]*30.0 - 15.0;
  double mh_q   = (double)f[9]*2.5 + 0.5;
  double ml_fc  = (double)f[10]*2300.0 + 200.0;
  double ml_g   = (double)f[11]*30.0 - 15.0;
  double ml_q   = (double)f[12]*2.5 + 0.5;
  double c_thr  = (double)f[13]*30.0 - 20.0;
  double c_rat  = (double)f[14]*19.0 + 1.0;
  double c_att  = (double)f[15]*29.0 + 1.0;
  double c_rel  = (double)f[16]*3900.0 + 100.0;
  double gain_out=(double)f[22]*60.0 - 48.0;
  double pan    = (double)f[23]*0.4 + 0.3;

  double B[18], A1[6], A2[6];
  { double K = tan(3.14159265358979323846*hp_fc/44100.0);
    double a1=(K-1.0)/(K+1.0), b0=1.0/(1.0+K);
    B[0]=b0; B[1]=-b0; B[2]=0.0; A1[0]=a1; A2[0]=0.0; }
  { double K = tan(3.14159265358979323846*lp_fc/44100.0);
    double a1=(K-1.0)/(K+1.0), b0=K/(1.0+K);
    B[3]=b0; B[4]=b0; B[5]=0.0; A1[1]=a1; A2[1]=0.0; }
  shelf_coefs(hs_fc, hs_g,  1.0, B, A1, A2, 2);
  shelf_coefs(ls_fc, ls_g, -1.0, B, A1, A2, 3);
  peak_coefs (mh_fc, mh_g, mh_q, B, A1, A2, 4);
  peak_coefs (ml_fc, ml_g, ml_q, B, A1, A2, 5);

  double gin = pow(10.0, gain_in/20.0);
  B[0]*=gin; B[1]*=gin; B[2]*=gin;  // fold input gain into section 0

  float* Pc = ws + OFS_P + ch*64;
  #pragma unroll
  for (int k=0;k<6;k++){
    Pc[k]    = (float)B[k*3+0];
    Pc[6+k]  = (float)B[k*3+1];
    Pc[12+k] = (float)B[k*3+2];
    Pc[18+k] = (float)A1[k];
    Pc[24+k] = (float)A2[k];
  }
  Pc[30] = (float)c_thr;
  Pc[31] = (float)(1.0 - 1.0/c_rat);
  Pc[32] = (float)exp(-1.0/(c_att*0.001*44100.0));
  Pc[33] = (float)exp(-1.0/(c_rel*0.001*44100.0));
  double fb   = (double)f[17]*0.28 + 0.7;
  double damp = (double)f[18]*0.4;
  double wet1 = 3.0*(double)f[19]*0.5*(1.0+(double)f[21]);
  double dryg = 2.0*(double)f[20];
  double gout = pow(10.0, gain_out/20.0);
  Pc[34] = (float)fb;
  Pc[35] = (float)damp;
  Pc[36] = (float)(wet1*gout);
  Pc[37] = (float)(dryg*gout/0.015);   // applied to xt (= comp*0.015)
  Pc[38] = (float)cos(pan*1.57079632679489662);
  Pc[39] = (float)sin(pan*1.57079632679489662);

  float* po = pout + ch*24;
  po[0]=(float)gain_in; po[1]=(float)hp_fc; po[2]=(float)lp_fc; po[3]=(float)hs_fc;
  po[4]=(float)hs_g; po[5]=(float)ls_fc; po[6]=(float)ls_g; po[7]=(float)mh_fc;
  po[8]=(float)mh_g; po[9]=(float)mh_q; po[10]=(float)ml_fc; po[11]=(float)ml_g;
  po[12]=(float)ml_q; po[13]=(float)c_thr; po[14]=(float)c_rat; po[15]=(float)c_att;
  po[16]=(float)c_rel; po[17]=f[17]; po[18]=f[18]; po[19]=f[19]; po[20]=f[20];
  po[21]=f[21]; po[22]=(float)gain_out; po[23]=(float)pan;
}

// ---------------- biquad cascade: chunked linear scan ----------------

__device__ __forceinline__ float bq_step(const float* b0, const float* b1, const float* b2,
                                         const float* a1, const float* a2,
                                         float* z1, float* z2, float s){
  #pragma unroll
  for (int k=0;k<6;k++){
    float y = fmaf(b0[k], s, z1[k]);
    z1[k] = fmaf(b1[k], s, fmaf(-a1[k], y, z2[k]));
    z2[k] = fmaf(b2[k], s, -a2[k]*y);
    s = y;
  }
  return s;
}

__device__ __forceinline__ void load_coefs(const float* Pc, float* b0, float* b1, float* b2,
                                           float* a1, float* a2){
  #pragma unroll
  for (int k=0;k<6;k++){
    b0[k]=Pc[k]; b1[k]=Pc[6+k]; b2[k]=Pc[12+k]; a1[k]=Pc[18+k]; a2[k]=Pc[24+k];
  }
}

__global__ void k_chunk1(const float* __restrict__ x, float* __restrict__ ws){
  int tg = blockIdx.x*64 + threadIdx.x;      // 32 * 140 tasks
  int ch = tg / 140, sub = tg % 140;
  if (ch >= NCH) return;
  const float* Pc = ws + OFS_P + ch*64;
  float b0[6],b1[6],b2[6],a1[6],a2[6];
  load_coefs(Pc,b0,b1,b2,a1,a2);
  float z1[6]={0,0,0,0,0,0}, z2[6]={0,0,0,0,0,0};

  if (sub < CCHUNK){
    const float4* xp = (const float4*)(x + ch*T + sub*LCHUNK);
    for (int j=0;j<LCHUNK/4;j++){
      float4 v = xp[j];
      bq_step(b0,b1,b2,a1,a2,z1,z2,v.x);
      bq_step(b0,b1,b2,a1,a2,z1,z2,v.y);
      bq_step(b0,b1,b2,a1,a2,z1,z2,v.z);
      bq_step(b0,b1,b2,a1,a2,z1,z2,v.w);
    }
    float* vo = ws + OFS_V + (ch*CCHUNK + sub)*12;
    #pragma unroll
    for (int k=0;k<6;k++){ vo[2*k]=z1[k]; vo[2*k+1]=z2[k]; }
  } else {
    int j = sub - CCHUNK;                    // unit state index 0..11
    if ((j & 1)==0) z1[j>>1]=1.0f; else z2[j>>1]=1.0f;
    for (int t=0;t<LCHUNK;t++) bq_step(b0,b1,b2,a1,a2,z1,z2,0.0f);
    float* mo = ws + OFS_M + ch*144 + j*12;  // column j
    #pragma unroll
    for (int k=0;k<6;k++){ mo[2*k]=z1[k]; mo[2*k+1]=z2[k]; }
  }
}

__global__ void k_chunk2(float* __restrict__ ws){
  int ch = threadIdx.x;
  if (ch >= NCH) return;
  const float* M = ws + OFS_M + ch*144;
  const float* V = ws + OFS_V + ch*CCHUNK*12;
  float*       Z = ws + OFS_Z + ch*CCHUNK*12;
  float z[12];
  #pragma unroll
  for (int i=0;i<12;i++) z[i]=0.0f;
  for (int c=0;c<CCHUNK;c++){
    #pragma unroll
    for (int i=0;i<12;i++) Z[c*12+i]=z[i];
    float zn[12];
    #pragma unroll
    for (int i=0;i<12;i++) zn[i]=V[c*12+i];
    #pragma unroll
    for (int j=0;j<12;j++){
      float zj = z[j];
      #pragma unroll
      for (int i=0;i<12;i++) zn[i] = fmaf(M[j*12+i], zj, zn[i]);
    }
    #pragma unroll
    for (int i=0;i<12;i++) z[i]=zn[i];
  }
}

// pass 3: re-run chunks with correct init; write biquad out (A), target (B1),
// and per-8-group min-affine composed intercepts (12-float records, 9 used):
//   F_8(g) = min_{j=0..8}( aA^j aR^(8-j) g + beta_j )  -- EXACT
__global__ void k_chunk3(const float* __restrict__ x, float* __restrict__ ws){
  int tg = blockIdx.x*64 + threadIdx.x;      // 4096
  int ch = tg >> 7, c = tg & (CCHUNK-1);
  const float* Pc = ws + OFS_P + ch*64;
  float b0[6],b1[6],b2[6],a1[6],a2[6];
  load_coefs(Pc,b0,b1,b2,a1,a2);
  float thr = Pc[30], rt = Pc[31];
  float aA = Pc[32], aR = Pc[33];
  float kA = 1.0f - aA, kR = 1.0f - aR;
  const float* Zi = ws + OFS_Z + (ch*CCHUNK + c)*12;
  float z1[6], z2[6];
  #pragma unroll
  for (int k=0;k<6;k++){ z1[k]=Zi[2*k]; z2[k]=Zi[2*k+1]; }
  const float4* xp = (const float4*)(x + ch*T + c*LCHUNK);
  float4* Ao  = (float4*)(ws + OFS_A  + (size_t)ch*T + c*LCHUNK);
  float4* B1o = (float4*)(ws + OFS_B1 + (size_t)ch*T + c*LCHUNK);
  float*  Ig  = ws + OFS_I + (size_t)ch*98304;

  for (int gg=0; gg<64; gg++){
    float4 v0 = xp[2*gg], v1 = xp[2*gg+1];
    float ya[8], Tv[8];
    ya[0]=bq_step(b0,b1,b2,a1,a2,z1,z2,v0.x);
    ya[1]=bq_step(b0,b1,b2,a1,a2,z1,z2,v0.y);
    ya[2]=bq_step(b0,b1,b2,a1,a2,z1,z2,v0.z);
    ya[3]=bq_step(b0,b1,b2,a1,a2,z1,z2,v0.w);
    ya[4]=bq_step(b0,b1,b2,a1,a2,z1,z2,v1.x);
    ya[5]=bq_step(b0,b1,b2,a1,a2,z1,z2,v1.y);
    ya[6]=bq_step(b0,b1,b2,a1,a2,z1,z2,v1.z);
    ya[7]=bq_step(b0,b1,b2,a1,a2,z1,z2,v1.w);
    #pragma unroll
    for (int s=0;s<8;s++)
      Tv[s] = fminf(0.0f, (thr - 6.0205999132796239f*log2f(fabsf(ya[s])+1e-6f))*rt);
    Ao[2*gg]   = make_float4(ya[0],ya[1],ya[2],ya[3]);
    Ao[2*gg+1] = make_float4(ya[4],ya[5],ya[6],ya[7]);
    B1o[2*gg]   = make_float4(Tv[0],Tv[1],Tv[2],Tv[3]);
    B1o[2*gg+1] = make_float4(Tv[4],Tv[5],Tv[6],Tv[7]);
    // DP: compose 8 min-affine steps; beta[j] = min intercept with j attack-steps
    float bb[9];
    bb[0] = kR*Tv[0]; bb[1] = kA*Tv[0];
    #pragma unroll
    for (int s=1;s<8;s++){
      float bA = kA*Tv[s], bR = kR*Tv[s];
      bb[s+1] = fmaf(aA, bb[s], bA);
      #pragma unroll
      for (int j=7;j>=1;j--){
        if (j<=s) bb[j] = fminf(fmaf(aA, bb[j-1], bA), fmaf(aR, bb[j], bR));
      }
      bb[0] = fmaf(aR, bb[0], bR);
    }
    int G = c*64 + gg;                         // global group index
    float* ig = Ig + (G>>5)*384 + (G&31)*12;   // block-major 12-float records
    *(float4*)(ig)   = make_float4(bb[0],bb[1],bb[2],bb[3]);
    *(float4*)(ig+4) = make_float4(bb[4],bb[5],bb[6],bb[7]);
    *(float4*)(ig+8) = make_float4(bb[8],0.0f,0.0f,0.0f);
  }
}

// ---------------- fused compressor-scan + freeverb --------------------------
// R10 structure (best measured): SB=256 blocks, 3 barriers/iter.
// Waves 0-3: phase A (LDS-only): g recovery (2x ds_read_b128 target loads),
//   gain, comb gather into haloed cH; phase B1: x prefetch, VH=8-tap FIR +
//   comb writes, allpass stages 1-3; phase B2: stage-4 (L=225) with 31-sample
//   cross-lane handoff via xfer + halo copy for next block.
// Wave 4: phase A: LDS-write staged I/B1 regs; phase B1: load (i+2) to regs,
//   lane 256 scans block i+1 via the composed group operator; B2: idle.
// Delay-base advance: double wrap (L=225 < SB=256).

__global__ __launch_bounds__(320) void k_verb(float* __restrict__ ws){
  const int LC[8] = {1116,1188,1277,1356,1422,1491,1557,1617};
  const int COFF[8] = {0,1116,2304,3581,4937,6359,7850,9407};
  const int LA[4] = {556,441,341,225};
  const int AOFF[4] = {0,556,997,1338};
  int ch = blockIdx.x, tid = threadIdx.x;
  __shared__ float cb[11024];
  __shared__ float ab[1563];
  __shared__ float cH[8][264];     // [k][8 halo + 256]
  __shared__ float xts[256];
  __shared__ float B1st[2][256];   // target staging, dbuf
  __shared__ float IldS[384];      // 32 group records x 12
  __shared__ float gB[2][32];      // group-boundary g, dbuf
  __shared__ float xfer[32];       // stage-3 outputs for samples 225..255
  const float* Pc = ws + OFS_P + ch*64;
  float fb = Pc[34], damp = Pc[35], wet1 = Pc[36], dryk = Pc[37];
  float aA = Pc[32], aR = Pc[33];
  float kA = 1.0f - aA, kR = 1.0f - aR;
  float omd = 1.0f - damp;
  float* Aio = ws + OFS_A + (size_t)ch*T;
  const float* B1c = ws + OFS_B1 + (size_t)ch*T;
  const float* IG  = ws + OFS_I + (size_t)ch*98304;
  for (int i=tid;i<11024;i+=320) cb[i]=0.0f;
  for (int i=tid;i<1563;i+=320)  ab[i]=0.0f;
  for (int i=tid;i<8*264;i+=320) ((float*)cH)[i]=0.0f;
  bool scanw = (tid >= 256);
  int sl = tid - 256;
  // FIR weights damp^d
  float w[VH];
  { float pw = 1.0f;
    #pragma unroll
    for (int d=0;d<VH;d++){ w[d]=pw; pw*=damp; } }
  // scan slopes s_j = aA^j aR^(8-j)
  float sj[9];
  { float pA = 1.0f;
    #pragma unroll
    for (int j=0;j<9;j++){ sj[j]=pA; pA*=aA; }
    float pR = 1.0f;
    #pragma unroll
    for (int j=8;j>=0;j--){ sj[j]*=pR; pR*=aR; } }
  int cbb[8] = {0,0,0,0,0,0,0,0};
  int abb[4] = {0,0,0,0};
  float gcarry = 0.0f;
  float4 iR0, iR1, bR;
  float xv = 0.0f;

  // ---- prologue: IldS=I(0); B1st[0]=t(0), B1st[1]=t(1); regs=I(1); xv=x(0) ----
  if (scanw){
    const float4* isrc = (const float4*)(IG);
    float4* idst = (float4*)IldS;
    idst[sl] = isrc[sl];
    if (sl < 32) idst[64+sl] = isrc[64+sl];
    iR0 = isrc[96+sl];
    if (sl < 32) iR1 = isrc[96+64+sl];
    const float4* bsrc = (const float4*)(B1c);
    ((float4*)B1st[0])[sl] = bsrc[sl];
    ((float4*)B1st[1])[sl] = bsrc[64+sl];
  }
  if (tid < 256) xv = Aio[tid];
  __syncthreads();
  if (tid == 256){
    float g = 0.0f;
    for (int m=0;m<32;m++){
      gB[0][m] = g;
      const float* Ip = &IldS[m*12];
      float f0=fmaf(sj[0],g,Ip[0]), f1=fmaf(sj[1],g,Ip[1]), f2=fmaf(sj[2],g,Ip[2]);
      float f3=fmaf(sj[3],g,Ip[3]), f4=fmaf(sj[4],g,Ip[4]), f5=fmaf(sj[5],g,Ip[5]);
      float f6=fmaf(sj[6],g,Ip[6]), f7=fmaf(sj[7],g,Ip[7]), f8=fmaf(sj[8],g,Ip[8]);
      g = fminf(fminf(fminf(f0,f1),fminf(f2,f3)),
                fminf(fminf(f4,f5),fminf(fminf(f6,f7),f8)));
    }
    gcarry = g;
  }
  __syncthreads();

  for (int i=0;i<NBLK;i++){
    int t0 = i<<8;
    int p = i & 1;
    float xt = 0.0f, acc = 0.0f, a = 0.0f;
    // ---------- phase A (LDS-only) ----------
    if (tid < 256){
      int m = tid>>3, r = tid&7;
      float g = gB[p][m];
      const float* Bl = B1st[p] + (m<<3);
      float4 q0 = *(const float4*)(Bl);
      float4 q1 = *(const float4*)(Bl+4);
      float tv[8] = {q0.x,q0.y,q0.z,q0.w,q1.x,q1.y,q1.z,q1.w};
      #pragma unroll
      for (int s=0;s<8;s++){
        if (s<=r){
          float tt = tv[s];
          g = fminf(fmaf(aA,g,kA*tt), fmaf(aR,g,kR*tt));
        }
      }
      xt = xv * exp2f(g*0.16609640474436813f) * 0.015f;
      xts[tid] = xt;
      #pragma unroll
      for (int k=0;k<8;k++){
        int idx = cbb[k]+tid; if (idx>=LC[k]) idx-=LC[k];
        float o = cb[COFF[k]+idx];
        cH[k][VH+tid] = omd*o;
        acc += o;
      }
    } else if (i+1 < NBLK){
      // wave4: LDS-write staged regs: IldS = I(i+1); B1st[(i+1)&1] = t(i+1)
      float4* idst = (float4*)IldS;
      idst[sl] = iR0;
      if (sl < 32) idst[64+sl] = iR1;
      if (i >= 1) ((float4*)B1st[(i+1)&1])[sl] = bR;
    }
    __syncthreads();
    // ---------- phase B1: issue globals first, then compute ----------
    if (tid < 256){
      if (i+1 < NBLK) xv = Aio[t0+256+tid];    // prefetch next x (drain covered)
      // FIR damping + comb writes
      #pragma unroll
      for (int k=0;k<8;k++){
        float s = 0.0f;
        #pragma unroll
        for (int d=0;d<VH;d++) s = fmaf(w[d], cH[k][VH+tid-d], s);
        int idx = cbb[k]+tid; if (idx>=LC[k]) idx-=LC[k];
        cb[COFF[k]+idx] = fmaf(fb, s, xt);
      }
      // allpass stages 1-3, per-lane registers (slots unique: SB <= L)
      a = acc;
      #pragma unroll
      for (int j=0;j<3;j++){
        int idx = abb[j]+tid; if (idx>=LA[j]) idx-=LA[j];
        float bv = ab[AOFF[j]+idx];
        ab[AOFF[j]+idx] = fmaf(0.5f, bv, a);
        a = bv - a;
      }
      if (tid >= 225) xfer[tid-225] = a;
    } else {
      if (i+2 < NBLK){                         // stage block i+2 into regs
        const float4* isrc = (const float4*)(IG + (size_t)(i+2)*384);
        iR0 = isrc[sl];
        if (sl < 32) iR1 = isrc[64+sl];
        const float4* bsrc = (const float4*)(B1c + (size_t)(i+2)*SB);
        bR = bsrc[sl];
      }
      if (tid == 256 && i+1 < NBLK){           // scan block i+1
        int q = (i+1)&1;
        float g = gcarry;
        #pragma unroll 4
        for (int m=0;m<32;m++){
          gB[q][m] = g;
          const float* Ip = &IldS[m*12];
          float f0=fmaf(sj[0],g,Ip[0]), f1=fmaf(sj[1],g,Ip[1]), f2=fmaf(sj[2],g,Ip[2]);
          float f3=fmaf(sj[3],g,Ip[3]), f4=fmaf(sj[4],g,Ip[4]), f5=fmaf(sj[5],g,Ip[5]);
          float f6=fmaf(sj[6],g,Ip[6]), f7=fmaf(sj[7],g,Ip[7]), f8=fmaf(sj[8],g,Ip[8]);
          g = fminf(fminf(fminf(f0,f1),fminf(f2,f3)),
                    fminf(fminf(f4,f5),fminf(fminf(f6,f7),f8)));
        }
        gcarry = g;
      }
    }
    __syncthreads();
    // ---------- phase B2: allpass stage 4 (L=225) + output ----------
    if (tid < 225){
      int idx = abb[3]+tid; if (idx>=225) idx-=225;
      float bv = ab[AOFF[3]+idx];
      float b  = fmaf(0.5f, bv, a);
      float y  = bv - a;
      Aio[t0+tid] = fmaf(y, wet1, xts[tid]*dryk);
      if (tid < 31){
        float a2 = xfer[tid];              // sample tid+225
        float y2 = b - a2;
        ab[AOFF[3]+idx] = fmaf(0.5f, b, a2);
        Aio[t0+225+tid] = fmaf(y2, wet1, xts[225+tid]*dryk);
      } else {
        ab[AOFF[3]+idx] = b;
      }
    } else if (tid >= 232 && tid < 288){
      int q = tid-232; int k = q/7, d = q%7;   // halo: prev block samples 249..255
      cH[k][1+d] = cH[k][257+d];
    }
    #pragma unroll
    for (int k=0;k<8;k++){ cbb[k]+=SB; if (cbb[k]>=LC[k]) cbb[k]-=LC[k]; }
    #pragma unroll
    for (int j=0;j<4;j++){
      abb[j]+=SB;
      if (abb[j]>=LA[j]) abb[j]-=LA[j];
      if (abb[j]>=LA[j]) abb[j]-=LA[j];   // L=225 < SB=256 needs 2nd wrap
    }
    __syncthreads();
  }
}

// ---------------- pan mix ----------------

__global__ void k_mix(const float* __restrict__ ws, float* __restrict__ out){
  int id = blockIdx.x*256 + threadIdx.x;   // 4*65536
  int t = id & (T-1), b = id >> 16;
  const float* Av = ws + OFS_A + (size_t)b*8*T + t;
  const float* P = ws + OFS_P;
  float s0=0.0f, s1=0.0f;
  #pragma unroll
  for (int n=0;n<8;n++){
    float v = Av[(size_t)n*T];
    int ch = b*8+n;
    s0 = fmaf(v, P[ch*64+38], s0);
    s1 = fmaf(v, P[ch*64+39], s1);
  }
  out[b*2*T + t]     = s0;
  out[b*2*T + T + t] = s1;
}

extern "C" void kernel_launch(void* const* d_in, const int* in_sizes, int n_in,
                              void* d_out, int out_size, void* d_ws, size_t ws_size,
                              hipStream_t stream) {
  const float* x = (const float*)d_in[0];
  const float* p = (const float*)d_in[1];
  float* out = (float*)d_out;
  float* ws  = (float*)d_ws;

  k_params<<<1, 64, 0, stream>>>(p, ws, out + 4*2*T);
  k_chunk1<<<70, 64, 0, stream>>>(x, ws);
  k_chunk2<<<1, 64, 0, stream>>>(ws);
  k_chunk3<<<64, 64, 0, stream>>>(x, ws);
  k_verb  <<<NCH, 320, 0, stream>>>(ws);
  k_mix   <<<(4*T)/256, 256, 0, stream>>>(ws, out);
}